// Round 3
// baseline (225.804 us; speedup 1.0000x reference)
//
#include <hip/hip_runtime.h>
#include <cstdint>
#include <cstddef>

// Problem constants (from reference setup_inputs)
#define BB 64
#define TT 256
#define DD 512
#define BK 32
#define TILEM 128

typedef short bf16x8 __attribute__((ext_vector_type(8)));  // 8 bf16 in 4 VGPRs
typedef float f32x4  __attribute__((ext_vector_type(4)));  // MFMA acc

typedef __attribute__((address_space(1))) const void* gptr_t;
typedef __attribute__((address_space(3))) void* sptr_t;

// fp32 -> bf16, round-half-up (1 add + shift; bias 2^-17, irrelevant vs threshold)
static __device__ __forceinline__ unsigned short f2bf(float x) {
  unsigned u = __builtin_bit_cast(unsigned, x) + 0x8000u;
  return (unsigned short)(u >> 16);
}

// Block: 256 threads (4 waves), one 128x128 tile of out_r & out_i per block.
// Staging: fp32 tiles DMA'd global->LDS via global_load_lds (dwordx4) — no VGPR
// round-trip, no converts in the staging phase, one vmcnt(0) drain per barrier.
// LDS: sT[4][BK=32][128] fp32 (64 KB). tile0=re@d0, 1=im@d0, 2=re@e0, 3=im@e0.
// Compute: fragments read as 8x ds_read_b32 fp32, w-scaled (A side) and
// converted to bf16 in-register, then 16x16x32 bf16 MFMA (m89 layouts).
__global__ __launch_bounds__(256, 2)
void ComplexMixture_54838142435828_kernel(const float* __restrict__ re,
                                          const float* __restrict__ im,
                                          const float* __restrict__ wt,
                                          float* __restrict__ out) {
  __shared__ __attribute__((aligned(16))) float sT[4 * BK * 128];  // 64 KB
  __shared__ float sw[TT];

  const int tid = threadIdx.x;

  // ---- XCD-cluster swizzle (neutral but harmless; keeps batch on one XCD) ----
  const int L = blockIdx.x;          // 0..1023
  const int c = L & 7;
  const int s = L >> 3;
  const int b  = c * 8 + (s >> 4);   // batch
  const int t5 = s & 15;
  const int d0 = (t5 >> 2) * TILEM;  // output row tile
  const int e0 = (t5 & 3) * TILEM;   // output col tile

  sw[tid] = wt[b * TT + tid];  // synced by loop-top barrier

  const int lane = tid & 63;
  const int wid  = tid >> 6;
  const int wm = (wid >> 1) * 64;    // wave row offset in tile
  const int wn = (wid & 1) * 64;     // wave col offset in tile
  const int quad = lane >> 4;        // k-octet selector
  const int l16  = lane & 15;

  // Staging role: wave wid DMAs tile wid. tiles {0,1}->cols d0, {2,3}->cols e0;
  // tiles {0,2} from re, {1,3} from im. Per instruction p (p=0..15): covers
  // k = 2p + (lane>>5), d = (lane&31)*4 .. +3  (1 KB contiguous LDS).
  const int scol = (wid & 2) ? e0 : d0;
  const float* sbase = (wid & 1) ? im : re;
  const int ksub  = lane >> 5;
  const int dloc4 = (lane & 31) * 4;

  f32x4 accR[4][4], accI[4][4];
  #pragma unroll
  for (int mt = 0; mt < 4; ++mt)
    #pragma unroll
    for (int nt = 0; nt < 4; ++nt) {
      accR[mt][nt] = (f32x4){0.f, 0.f, 0.f, 0.f};
      accI[mt][nt] = (f32x4){0.f, 0.f, 0.f, 0.f};
    }

  for (int kt = 0; kt < TT; kt += BK) {
    __syncthreads();  // previous iter's LDS readers done (also covers sw init)

    // ---------------- stage global -> LDS (raw fp32, DMA) -------------------
    const float* gsrc = sbase + ((size_t)(b * TT + kt + ksub)) * DD + scol + dloc4;
    float* lbase = &sT[wid * (BK * 128)];
    #pragma unroll
    for (int p = 0; p < 16; ++p) {
      __builtin_amdgcn_global_load_lds((gptr_t)(const void*)(gsrc + (size_t)(2 * p) * DD),
                                       (sptr_t)(void*)(lbase + p * 256),
                                       16, 0, 0);
    }
    __syncthreads();  // barrier drains vmcnt(0) -> DMA complete

    // ---------------- compute: one MFMA K=32 step ---------------------------
    // 8 weights for this lane's k-octet (broadcast within quad, 4 banks total)
    float wv[8];
    #pragma unroll
    for (int j = 0; j < 8; ++j) wv[j] = sw[kt + quad * 8 + j];

    // B fragments (unscaled): B[e=l16][k=quad*8+j]
    bf16x8 bR[4], bI[4];
    #pragma unroll
    for (int nt = 0; nt < 4; ++nt) {
      const int dl = wn + nt * 16 + l16;
      union { unsigned short h[8]; bf16x8 v; } ur, ui;
      #pragma unroll
      for (int j = 0; j < 8; ++j) {
        ur.h[j] = f2bf(sT[2 * (BK * 128) + (quad * 8 + j) * 128 + dl]);
        ui.h[j] = f2bf(sT[3 * (BK * 128) + (quad * 8 + j) * 128 + dl]);
      }
      bR[nt] = ur.v;
      bI[nt] = ui.v;
    }

    #pragma unroll
    for (int mt = 0; mt < 4; ++mt) {
      const int dl = wm + mt * 16 + l16;
      union { unsigned short h[8]; bf16x8 v; } ur, ui;
      #pragma unroll
      for (int j = 0; j < 8; ++j) {
        const float r = sT[0 * (BK * 128) + (quad * 8 + j) * 128 + dl] * wv[j];
        const float i = sT[1 * (BK * 128) + (quad * 8 + j) * 128 + dl] * wv[j];
        ur.h[j] = f2bf(r);
        ui.h[j] = f2bf(i);
      }
      const bf16x8 aR = ur.v;
      const bf16x8 aI = ui.v;
      const bf16x8 aRn = aR ^ (bf16x8)((short)0x8000);  // -(w*R) via sign flip
      #pragma unroll
      for (int nt = 0; nt < 4; ++nt) {
        accR[mt][nt] = __builtin_amdgcn_mfma_f32_16x16x32_bf16(aR,  bR[nt], accR[mt][nt], 0, 0, 0);
        accR[mt][nt] = __builtin_amdgcn_mfma_f32_16x16x32_bf16(aI,  bI[nt], accR[mt][nt], 0, 0, 0);
        accI[mt][nt] = __builtin_amdgcn_mfma_f32_16x16x32_bf16(aI,  bR[nt], accI[mt][nt], 0, 0, 0);
        accI[mt][nt] = __builtin_amdgcn_mfma_f32_16x16x32_bf16(aRn, bI[nt], accI[mt][nt], 0, 0, 0);
      }
    }
  }

  // ---------------- epilogue: C/D layout col=lane&15, row=quad*4+reg (m89) ----
  const size_t NOFF = (size_t)BB * DD * DD;  // out_i offset in flat tuple output
  #pragma unroll
  for (int mt = 0; mt < 4; ++mt) {
    #pragma unroll
    for (int r = 0; r < 4; ++r) {
      const int drow = d0 + wm + mt * 16 + quad * 4 + r;
      const size_t rowOff = ((size_t)(b * DD + drow)) * DD;
      #pragma unroll
      for (int nt = 0; nt < 4; ++nt) {
        const int ecol = e0 + wn + nt * 16 + l16;
        out[rowOff + ecol]        = accR[mt][nt][r];
        out[NOFF + rowOff + ecol] = accI[mt][nt][r];
      }
    }
  }
}

extern "C" void kernel_launch(void* const* d_in, const int* in_sizes, int n_in,
                              void* d_out, int out_size, void* d_ws, size_t ws_size,
                              hipStream_t stream) {
  const float* re = (const float*)d_in[0];
  const float* im = (const float*)d_in[1];
  const float* wt = (const float*)d_in[2];
  float* out = (float*)d_out;
  ComplexMixture_54838142435828_kernel<<<dim3(1024), dim3(256), 0, stream>>>(re, im, wt, out);
}

// Round 4
// 220.704 us; speedup vs baseline: 1.0231x; 1.0231x over previous
//
#include <hip/hip_runtime.h>
#include <cstdint>
#include <cstddef>

// Problem constants
#define BB 64
#define TT 256
#define DD 512
#define BK 16
#define TILEM 128

typedef short bf16x8 __attribute__((ext_vector_type(8)));   // 8 bf16 (4 VGPRs)
typedef float f32x16 __attribute__((ext_vector_type(16)));  // 32x32 MFMA acc
typedef float f32x4v __attribute__((ext_vector_type(4)));

typedef __attribute__((address_space(1))) const void* gptr_t;
typedef __attribute__((address_space(3))) void* sptr_t;

// fp32 -> bf16, round-half-up
static __device__ __forceinline__ unsigned short f2bf(float x) {
  unsigned u = __builtin_bit_cast(unsigned, x) + 0x8000u;
  return (unsigned short)(u >> 16);
}

// Symmetry: out_r symmetric, out_i antisymmetric => compute only the 10
// lower-triangle 128x128 tiles per batch; mirror the 6 off-diagonal ones.
// Block: 256 threads (4 waves), wave tile 64x64 = 2x2 of 32x32x16 bf16 MFMA.
// Staging: distance-1 pipelined global_load_lds DMA, BK=16 double-buffered
// fp32 stages sT[2][4][16][128] (64 KB). tile0=re@d0,1=im@d0,2=re@e0,3=im@e0.
// w-scale + bf16 convert at fragment-read time (conflict-free ds_read_b32).
#define STG(buf, t, idx) sB[(buf) * 8192 + (t) * 2048 + (idx)]

__global__ __launch_bounds__(256, 2)
void ComplexMixture_54838142435828_kernel(const float* __restrict__ re,
                                          const float* __restrict__ im,
                                          const float* __restrict__ wt,
                                          float* __restrict__ out) {
  // 16896 floats = 67584 B: covers 2*4*2048 (stages) and 128*132 (transpose pad)
  __shared__ __attribute__((aligned(16))) float sB[16896];
  __shared__ float sw[TT];

  const int tid = threadIdx.x;
  const int b = blockIdx.y;
  static const int TIa[10] = {0, 1, 1, 2, 2, 2, 3, 3, 3, 3};
  static const int TJa[10] = {0, 0, 1, 0, 1, 2, 0, 1, 2, 3};
  const int d0 = TIa[blockIdx.x] * TILEM;  // row tile (>= col tile)
  const int e0 = TJa[blockIdx.x] * TILEM;  // col tile

  sw[tid] = wt[b * TT + tid];  // covered by first loop barrier

  const int lane = tid & 63;
  const int wid  = tid >> 6;
  const int wm = (wid >> 1) * 64;  // wave row offset
  const int wn = (wid & 1) * 64;   // wave col offset
  const int kh  = lane >> 5;       // k-half selector (32x32x16: k = kh*8 + j)
  const int l32 = lane & 31;

  // Staging role: wave wid DMAs tile wid; 8x dwordx4 per stage.
  const float* sbase = (wid & 1) ? im : re;
  const int scol = (wid & 2) ? e0 : d0;
  const int dl4  = l32 * 4;

  f32x16 accR[2][2], accI[2][2];
  #pragma unroll
  for (int mt = 0; mt < 2; ++mt)
    #pragma unroll
    for (int nt = 0; nt < 2; ++nt) {
      #pragma unroll
      for (int r = 0; r < 16; ++r) { accR[mt][nt][r] = 0.f; accI[mt][nt][r] = 0.f; }
    }

  auto stage = [&](int it, int buf) {
    const float* g = sbase + ((size_t)(b * TT + it * BK + kh)) * DD + scol + dl4;
    const int lb = buf * 8192 + wid * 2048;
    #pragma unroll
    for (int p = 0; p < 8; ++p) {
      __builtin_amdgcn_global_load_lds((gptr_t)(const void*)(g + (size_t)(2 * p) * DD),
                                       (sptr_t)(void*)&sB[lb + p * 256], 16, 0, 0);
    }
  };

  stage(0, 0);  // prologue

  for (int it = 0; it < TT / BK; ++it) {
    __syncthreads();  // drains vmcnt(0): stage(it) landed; prev readers done
    if (it < TT / BK - 1) stage(it + 1, (it + 1) & 1);  // distance-1 prefetch
    const int buf = it & 1;

    float wv[8];
    #pragma unroll
    for (int j = 0; j < 8; ++j) wv[j] = sw[it * BK + kh * 8 + j];

    // A fragments (w-scaled): A[m = wm+mt*32+l32][k = kh*8+j]
    bf16x8 aR[2], aI[2], bR[2], bI[2];
    #pragma unroll
    for (int mt = 0; mt < 2; ++mt) {
      const int m = wm + mt * 32 + l32;
      union { unsigned short h[8]; bf16x8 v; } ur, ui;
      #pragma unroll
      for (int j = 0; j < 8; ++j) {
        const int idx = (kh * 8 + j) * 128 + m;
        ur.h[j] = f2bf(STG(buf, 0, idx) * wv[j]);
        ui.h[j] = f2bf(STG(buf, 1, idx) * wv[j]);
      }
      aR[mt] = ur.v; aI[mt] = ui.v;
    }
    // B fragments (unscaled): B[n = wn+nt*32+l32][k = kh*8+j]
    #pragma unroll
    for (int nt = 0; nt < 2; ++nt) {
      const int n = wn + nt * 32 + l32;
      union { unsigned short h[8]; bf16x8 v; } ur, ui;
      #pragma unroll
      for (int j = 0; j < 8; ++j) {
        const int idx = (kh * 8 + j) * 128 + n;
        ur.h[j] = f2bf(STG(buf, 2, idx));
        ui.h[j] = f2bf(STG(buf, 3, idx));
      }
      bR[nt] = ur.v; bI[nt] = ui.v;
    }

    #pragma unroll
    for (int mt = 0; mt < 2; ++mt) {
      const bf16x8 aRn = aR[mt] ^ (bf16x8)((short)0x8000);  // -(w*R)
      #pragma unroll
      for (int nt = 0; nt < 2; ++nt) {
        accR[mt][nt] = __builtin_amdgcn_mfma_f32_32x32x16_bf16(aR[mt], bR[nt], accR[mt][nt], 0, 0, 0);
        accR[mt][nt] = __builtin_amdgcn_mfma_f32_32x32x16_bf16(aI[mt], bI[nt], accR[mt][nt], 0, 0, 0);
        accI[mt][nt] = __builtin_amdgcn_mfma_f32_32x32x16_bf16(aI[mt], bR[nt], accI[mt][nt], 0, 0, 0);
        accI[mt][nt] = __builtin_amdgcn_mfma_f32_32x32x16_bf16(aRn,    bI[nt], accI[mt][nt], 0, 0, 0);
      }
    }
  }

  // ---- epilogue: straight stores. C/D (m74/m101): col=lane&31, row=(r&3)+8*(r>>2)+4*kh
  const size_t NOFF = (size_t)BB * DD * DD;
  #pragma unroll
  for (int mt = 0; mt < 2; ++mt) {
    #pragma unroll
    for (int r = 0; r < 16; ++r) {
      const int row_l = (r & 3) + 8 * (r >> 2) + 4 * kh;
      const size_t rowOff = ((size_t)(b * DD + d0 + wm + mt * 32 + row_l)) * DD;
      #pragma unroll
      for (int nt = 0; nt < 2; ++nt) {
        const int col = e0 + wn + nt * 32 + l32;
        out[rowOff + col]        = accR[mt][nt][r];
        out[NOFF + rowOff + col] = accI[mt][nt][r];
      }
    }
  }

  // ---- mirror passes (off-diagonal only): sM[c*132 + r] col-major, pad 132
  if (d0 != e0) {
    #pragma unroll
    for (int pass = 0; pass < 2; ++pass) {
      __syncthreads();  // previous readers of sB done
      #pragma unroll
      for (int mt = 0; mt < 2; ++mt)
        #pragma unroll
        for (int nt = 0; nt < 2; ++nt)
          #pragma unroll
          for (int r = 0; r < 16; ++r) {
            const int rr = wm + mt * 32 + (r & 3) + 8 * (r >> 2) + 4 * kh;
            const int cc = wn + nt * 32 + l32;
            sB[cc * 132 + rr] = pass == 0 ? accR[mt][nt][r] : -accI[mt][nt][r];
          }
      __syncthreads();
      const size_t base = (pass == 0 ? (size_t)0 : NOFF) + (size_t)b * DD * DD;
      #pragma unroll 4
      for (int q = 0; q < 16; ++q) {
        const int c  = q * 8 + (tid >> 5);   // source col = target row offset
        const int r4 = (tid & 31) * 4;       // source row = target col (x4 vector)
        f32x4v v = *(const f32x4v*)&sB[c * 132 + r4];
        *(f32x4v*)&out[base + (size_t)(e0 + c) * DD + d0 + r4] = v;
      }
    }
  }
}

extern "C" void kernel_launch(void* const* d_in, const int* in_sizes, int n_in,
                              void* d_out, int out_size, void* d_ws, size_t ws_size,
                              hipStream_t stream) {
  const float* re = (const float*)d_in[0];
  const float* im = (const float*)d_in[1];
  const float* wt = (const float*)d_in[2];
  float* out = (float*)d_out;
  ComplexMixture_54838142435828_kernel<<<dim3(10, BB), dim3(256), 0, stream>>>(re, im, wt, out);
}